// Round 4
// baseline (56.564 us; speedup 1.0000x reference)
//
#include <hip/hip_runtime.h>

// Problem constants (from reference): B=64, H=W=512, 256 zones.
#define NZ    256
#define NB    64
#define NPIX  (512 * 512)

// Pass-1 geometry: 32 elems/thread -> 2048 blocks, 1 KB partial table each.
#define EPT1  32
#define CHUNK1 (256 * EPT1)        // 8192 px per block
#define BPB1  (NPIX / CHUNK1)      // 32 blocks per batch
#define NBLK1 (NB * BPB1)          // 2048

// Pass-3 geometry: 16 elems/thread -> 4096 blocks (R2 showed ~13us here).
#define CHUNK3 (256 * 16)
#define BPB3  (NPIX / CHUNK3)      // 64
#define NBLK3 (NB * BPB3)          // 4096

// Monotonic float->unsigned encoding: preserves total order.
// enc()==0 only for bits 0xFFFFFFFF (a NaN) -> safe "empty" sentinel; dec(0)=NaN.
__device__ __forceinline__ unsigned enc(float f) {
    unsigned b = __float_as_uint(f);
    return b ^ ((b & 0x80000000u) ? 0xFFFFFFFFu : 0x80000000u);
}
__device__ __forceinline__ float dec(unsigned u) {
    unsigned b = (u & 0x80000000u) ? (u ^ 0x80000000u) : ~u;
    return __uint_as_float(b);
}

// Pass 1: per-block LDS segmax over 8192 consecutive pixels.
// R3 evidence: the DS-atomic pipe (16.7M scattered LDS RMW ops, ~70 cyc/wave-op)
// is the bottleneck, not memory (mask_kernel streams the same bytes at 15 TB/s).
// Fix: READ-FILTER each atomic. After warm-up only ~1/k of pixels beat the
// running zone max, so ~90% of RMW ops become cheap (broadcastable) ds_reads,
// and the surviving atomics have few active lanes -> few conflicts.
// Race-safe: if e > final max then e > every intermediate value -> atomic runs.
__global__ __launch_bounds__(256) void segmax_part(
        const float* __restrict__ inp, const int* __restrict__ zones,
        unsigned* __restrict__ part) {
    __shared__ unsigned smax[NZ];
    const int t = threadIdx.x;
    smax[t] = 0u;  // blockDim == NZ == 256
    __syncthreads();

    const int batch = blockIdx.x / BPB1;
    const int chunk = blockIdx.x % BPB1;
    const long base = (long)batch * NPIX + (long)chunk * CHUNK1;
    const float4* in4 = (const float4*)(inp + base);
    const int4*   z4  = (const int4*)(zones + base);

#pragma unroll
    for (int h = 0; h < EPT1 / 16; ++h) {
        unsigned e[16];
        int      zi[16];
#pragma unroll
        for (int i = 0; i < 4; ++i) {
            const int idx = (h * 4 + i) * 256 + t;
            float4 v = in4[idx];
            int4   z = z4[idx];
            e[4 * i + 0] = enc(v.x); zi[4 * i + 0] = z.x;
            e[4 * i + 1] = enc(v.y); zi[4 * i + 1] = z.y;
            e[4 * i + 2] = enc(v.z); zi[4 * i + 2] = z.z;
            e[4 * i + 3] = enc(v.w); zi[4 * i + 3] = z.w;
        }
        unsigned cur[16];
#pragma unroll
        for (int j = 0; j < 16; ++j) cur[j] = smax[zi[j]];   // filter reads
#pragma unroll
        for (int j = 0; j < 16; ++j)
            if (e[j] > cur[j]) atomicMax(&smax[zi[j]], e[j]); // rare RMW
    }
    __syncthreads();
    part[(long)blockIdx.x * NZ + t] = smax[t];  // coalesced 1 KB store
}

// Pass 2: one block per batch; thread t max-combines zone t over the batch's
// 32 chunk tables (stride-NZ reads coalesce across threads) and stores the
// DECODED float (empty zone -> dec(0)=NaN, matches no pixel).
__global__ __launch_bounds__(256) void segmax_reduce(
        const unsigned* __restrict__ part, float* __restrict__ segf) {
    const int t = threadIdx.x;
    const int batch = blockIdx.x;
    const unsigned* p = part + (long)batch * BPB1 * NZ;
    unsigned m = 0u;
#pragma unroll 8
    for (int c = 0; c < BPB1; ++c) m = max(m, p[c * NZ + t]);
    segf[batch * NZ + t] = dec(m);
}

// Pass 3: mask = (x == segmax[zone]) as int32 0/1; per-block partial count to
// a private slot (contended global atomicAdd was the 192us R1 bug).
__global__ __launch_bounds__(256) void mask_kernel(
        const float* __restrict__ inp, const int* __restrict__ zones,
        const float* __restrict__ segf,
        int* __restrict__ mask, int* __restrict__ partial) {
    __shared__ float smax[NZ];
    __shared__ int wsum[4];
    const int t = threadIdx.x;

    const int batch = blockIdx.x / BPB3;
    const int chunk = blockIdx.x % BPB3;

    smax[t] = segf[batch * NZ + t];
    __syncthreads();

    const long base = (long)batch * NPIX + (long)chunk * CHUNK3;
    const float4* in4 = (const float4*)(inp + base);
    const int4*   z4  = (const int4*)(zones + base);
    int4* m4 = (int4*)(mask + base);

    int c = 0;
#pragma unroll
    for (int it = 0; it < 4; ++it) {
        float4 v = in4[it * 256 + t];
        int4   z = z4[it * 256 + t];
        int4 m;
        m.x = (v.x == smax[z.x]) ? 1 : 0;
        m.y = (v.y == smax[z.y]) ? 1 : 0;
        m.z = (v.z == smax[z.z]) ? 1 : 0;
        m.w = (v.w == smax[z.w]) ? 1 : 0;
        m4[it * 256 + t] = m;
        c += m.x + m.y + m.z + m.w;
    }

#pragma unroll
    for (int off = 32; off; off >>= 1) c += __shfl_down(c, off);
    if ((t & 63) == 0) wsum[t >> 6] = c;
    __syncthreads();
    if (t == 0) partial[blockIdx.x] = wsum[0] + wsum[1] + wsum[2] + wsum[3];
}

// Pass 4: single block sums the 4096 partials into the output counter.
__global__ __launch_bounds__(256) void count_kernel(
        const int* __restrict__ partial, int n, int* __restrict__ count) {
    __shared__ int wsum[4];
    const int t = threadIdx.x;
    int c = 0;
    for (int i = t; i < n; i += 256) c += partial[i];
#pragma unroll
    for (int off = 32; off; off >>= 1) c += __shfl_down(c, off);
    if ((t & 63) == 0) wsum[t >> 6] = c;
    __syncthreads();
    if (t == 0) *count = wsum[0] + wsum[1] + wsum[2] + wsum[3];
}

extern "C" void kernel_launch(void* const* d_in, const int* in_sizes, int n_in,
                              void* d_out, int out_size, void* d_ws, size_t ws_size,
                              hipStream_t stream) {
    const float* inp   = (const float*)d_in[0];
    const int*   zones = (const int*)d_in[1];
    int*         out   = (int*)d_out;   // [B*NPIX] mask + [1] n_centers, int32

    // Workspace layout (all fully overwritten every call -> no memset needed,
    // deterministic under graph replay):
    //   part   : NBLK1*NZ u32 = 2 MB
    //   segf   : NB*NZ   f32  = 64 KB
    //   partial: NBLK3   i32  = 16 KB
    unsigned* part    = (unsigned*)d_ws;
    float*    segf    = (float*)((char*)d_ws + (size_t)NBLK1 * NZ * 4);
    int*      partial = (int*)((char*)d_ws + (size_t)NBLK1 * NZ * 4 + (size_t)NB * NZ * 4);

    const long nmask = (long)NB * NPIX;  // == out_size - 1

    segmax_part  <<<NBLK1, 256, 0, stream>>>(inp, zones, part);
    segmax_reduce<<<NB,    256, 0, stream>>>(part, segf);
    mask_kernel  <<<NBLK3, 256, 0, stream>>>(inp, zones, segf, out, partial);
    count_kernel <<<1,     256, 0, stream>>>(partial, NBLK3, out + nmask);
}